// Round 11
// baseline (214.829 us; speedup 1.0000x reference)
//
#include <hip/hip_runtime.h>
#include <stdint.h>

// Problem constants (B=2,S=1024,D=1024,F=4096,E=8)
#define T_TOK 2048
#define D_DIM 1024
#define F_DIM 4096
#define E_NUM 8
#define RPMAX 3072   // max padded rows: sum of per-expert ceil(cnt,128)
#define BK 64

typedef __attribute__((ext_vector_type(8))) short bfx8;   // 8 bf16 (4 VGPR)
typedef __attribute__((ext_vector_type(4))) float fx4;    // MFMA accum

__device__ __forceinline__ unsigned short f2bf(float f) {
  union { float f; uint32_t u; } v; v.f = f;
  uint32_t u = v.u;
  u += 0x7FFFu + ((u >> 16) & 1u);   // round-to-nearest-even
  return (unsigned short)(u >> 16);
}

__device__ __forceinline__ void load_lds16(const unsigned short* g, unsigned short* l) {
  __builtin_amdgcn_global_load_lds(
      (const __attribute__((address_space(1))) void*)g,
      (__attribute__((address_space(3))) void*)l, 16, 0, 0);
}

// ---------------- router: logits, softmax, argmax; NO global atomics ----------------
__global__ __launch_bounds__(256) void router_kernel(
    const float* __restrict__ x, const float* __restrict__ sw,
    const float* __restrict__ sb, float* __restrict__ pmax_out,
    int* __restrict__ routes, float* __restrict__ probs,
    unsigned short* __restrict__ xbf) {
  const int wave = threadIdx.x >> 6, lane = threadIdx.x & 63;
  const int t = blockIdx.x * 4 + wave;
  const float* xr = x + (size_t)t * D_DIM;
  float acc[8];
#pragma unroll
  for (int e = 0; e < 8; ++e) acc[e] = 0.f;
#pragma unroll
  for (int i = 0; i < 4; ++i) {
    const int d = i * 256 + lane * 4;
    float4 xv = *(const float4*)(xr + d);
    ushort4 h;
    h.x = f2bf(xv.x); h.y = f2bf(xv.y); h.z = f2bf(xv.z); h.w = f2bf(xv.w);
    *(ushort4*)(xbf + (size_t)t * D_DIM + d) = h;
    const float xs[4] = {xv.x, xv.y, xv.z, xv.w};
#pragma unroll
    for (int j = 0; j < 4; ++j) {
      const float4* swp = (const float4*)(sw + (size_t)(d + j) * 8);
      float4 w0 = swp[0], w1 = swp[1];
      acc[0] += xs[j] * w0.x; acc[1] += xs[j] * w0.y;
      acc[2] += xs[j] * w0.z; acc[3] += xs[j] * w0.w;
      acc[4] += xs[j] * w1.x; acc[5] += xs[j] * w1.y;
      acc[6] += xs[j] * w1.z; acc[7] += xs[j] * w1.w;
    }
  }
#pragma unroll
  for (int e = 0; e < 8; ++e) {
    float v = acc[e];
    for (int o = 32; o > 0; o >>= 1) v += __shfl_down(v, o, 64);
    acc[e] = v;
  }
  if (lane == 0) {
#pragma unroll
    for (int e = 0; e < 8; ++e) acc[e] += sb[e];
    int am = 0; float mx = acc[0];
#pragma unroll
    for (int e = 1; e < 8; ++e) if (acc[e] > mx) { mx = acc[e]; am = e; }  // first-max wins
    float p[8]; float s = 0.f;
#pragma unroll
    for (int e = 0; e < 8; ++e) { p[e] = expf(acc[e] - mx); s += p[e]; }
    float inv = 1.0f / s;
    pmax_out[t] = inv;
    routes[t] = am;
#pragma unroll
    for (int e = 0; e < 8; ++e) probs[(size_t)t * 8 + e] = p[e] * inv;
  }
}

// -------- plan: counts/psums reduce, offsets, perm init, scatter (fused) --------
__global__ __launch_bounds__(256) void plan_kernel(
    const int* __restrict__ routes, const float* __restrict__ probs,
    int* __restrict__ off, int* __restrict__ perm_out, int* __restrict__ perm_src,
    float* __restrict__ out_counts, float* __restrict__ out_psums,
    float* __restrict__ out_zero) {
  __shared__ int cnt[8];
  __shared__ int cur[8];
  __shared__ int offs[9];
  __shared__ float red[256][8];
  const int tid = threadIdx.x;
  if (tid < 8) cnt[tid] = 0;
  for (int i = tid; i < RPMAX; i += 256) { perm_out[i] = -1; perm_src[i] = 0; }
  __syncthreads();
  float loc[8];
#pragma unroll
  for (int e = 0; e < 8; ++e) loc[e] = 0.f;
  for (int t = tid; t < T_TOK; t += 256) {
    atomicAdd(&cnt[routes[t]], 1);
    const float4* p = (const float4*)(probs + (size_t)t * 8);
    float4 a = p[0], b = p[1];
    loc[0] += a.x; loc[1] += a.y; loc[2] += a.z; loc[3] += a.w;
    loc[4] += b.x; loc[5] += b.y; loc[6] += b.z; loc[7] += b.w;
  }
#pragma unroll
  for (int e = 0; e < 8; ++e) red[tid][e] = loc[e];
  __syncthreads();
  for (int s = 128; s >= 1; s >>= 1) {
    if (tid < s) {
#pragma unroll
      for (int e = 0; e < 8; ++e) red[tid][e] += red[tid + s][e];
    }
    __syncthreads();
  }
  if (tid == 0) {
    int o = 0;
    for (int e = 0; e < 8; ++e) { offs[e] = o; o += ((cnt[e] + 127) >> 7) << 7; }
    offs[8] = o;
    *out_zero = 0.0f;
  }
  __syncthreads();
  if (tid < 9) off[tid] = offs[tid];
  if (tid < 8) {
    cur[tid] = offs[tid];
    out_counts[tid] = (float)cnt[tid];
    out_psums[tid] = red[0][tid];
  }
  __syncthreads();
  for (int t = tid; t < T_TOK; t += 256) {
    int e = routes[t];
    int pos = atomicAdd(&cur[e], 1);
    perm_out[pos] = t;
    perm_src[pos] = t;
  }
}

// ---------------- convert+transpose: W fp32 [E][K][N] -> bf16 [E][N][K] ----------------
template <int K_, int N_>
__global__ __launch_bounds__(256) void conv_kernel(
    const float* __restrict__ W, unsigned short* __restrict__ WT) {
  __shared__ unsigned short tile[64][34];   // [k][n], pad to 34 u16
  const int t = threadIdx.x;
  const int nbase = blockIdx.x * 32;
  const int kbase = blockIdx.y * 64;
  const int e = blockIdx.z;
  const float* We = W + (size_t)e * K_ * N_;
  unsigned short* WTe = WT + (size_t)e * N_ * K_;
  {
    int kl = t >> 2;               // 0..63
    int nc = (t & 3) * 8;          // 0..24 step 8
    const float4* src = (const float4*)(We + (size_t)(kbase + kl) * N_ + nbase + nc);
    float4 a = src[0], b = src[1];
    unsigned short u[8] = {f2bf(a.x), f2bf(a.y), f2bf(a.z), f2bf(a.w),
                           f2bf(b.x), f2bf(b.y), f2bf(b.z), f2bf(b.w)};
#pragma unroll
    for (int p = 0; p < 4; ++p) {
      uint32_t pk = (uint32_t)u[2 * p] | ((uint32_t)u[2 * p + 1] << 16);
      *(uint32_t*)&tile[kl][nc + 2 * p] = pk;
    }
  }
  __syncthreads();
  {
    int nl = t >> 3;               // 0..31
    int kc = (t & 7) * 8;          // 0..56 step 8
    bfx8 v;
#pragma unroll
    for (int i = 0; i < 8; ++i) v[i] = (short)tile[kc + i][nl];
    *(bfx8*)(WTe + (size_t)(nbase + nl) * K_ + kbase + kc) = v;
  }
}

// ---------------- grouped GEMM, 2-phase, compiler-managed sync ----------------
// BMxBN tile, BK=64, 4 waves (2m x 2n). BOTH operands bf16 via global_load_lds
// (pre-swizzled per-lane source, key row&7; LDS linear), double-buffered.
// Per K-step: STAGE(t+1) [pure DMA] -> COMPUTE(t) (ds_read_b128 + MFMA) ->
// __syncthreads() (real fence: compiler emits vmcnt(0) lgkmcnt(0) + s_barrier;
// no hand-rolled asm barrier -> no DMA-hoist race; m97/m248 proven shape).
template <int BM, int BN, int K_, int N_, bool FIRST, bool NCHUNK>
__global__ __launch_bounds__(256, 2) void gemm2ph(
    const unsigned short* __restrict__ A,    // FIRST: xbf [T][K_]; else H [RP][K_]
    const unsigned short* __restrict__ WT,   // [E][N_][K_] bf16
    const float* __restrict__ Bias,          // [E][N_]
    const int* __restrict__ off,
    const int* __restrict__ perm_src, const int* __restrict__ perm_out,
    const float* __restrict__ pmax,
    unsigned short* __restrict__ Hout, float* __restrict__ Out) {
  constexpr int NT = K_ / BK;
  constexpr int FM = BM / 32, FN = BN / 32;   // frags per wave (wave out = BM/2 x BN/2)
  constexpr int AC = BM / 32, BC = BN / 32;   // DMA instrs per wave
  __shared__ __align__(16) unsigned short As[2][BM * 64];
  __shared__ __align__(16) unsigned short Bs[2][BN * 64];
  const int tid = threadIdx.x;
  // XCD-chunked bijective swizzle (grid size multiple of 8)
  const int nbx = gridDim.x, nby = gridDim.y;
  const int lin = blockIdx.y * nbx + blockIdx.x;
  const int chunkg = (nbx * nby) >> 3;
  const int newlin = (lin & 7) * chunkg + (lin >> 3);
  const int bx = NCHUNK ? (newlin / nby) : (newlin % nbx);
  const int by = NCHUNK ? (newlin % nby) : (newlin / nbx);
  const int rowbase = by * BM;
  if (rowbase >= off[8]) return;
  int e = 0;
#pragma unroll
  for (int i = 1; i <= 7; ++i) if (rowbase >= off[i]) e = i;
  const int n0 = bx * BN;
  const int wave = tid >> 6, lane = tid & 63;
  const int wm = wave >> 1, wn = wave & 1;

  // per-lane pre-swizzled global sources (m173): LDS linear, src chunk XOR'd
  const unsigned short* aSrc[AC];
#pragma unroll
  for (int c = 0; c < AC; ++c) {
    int ca = (wave * AC + c) * 64 + lane;
    int row = ca >> 3, slot = ca & 7;
    int sc = slot ^ (row & 7);
    size_t arow = FIRST ? (size_t)perm_src[rowbase + row] : (size_t)(rowbase + row);
    aSrc[c] = A + arow * K_ + sc * 8;
  }
  const unsigned short* bSrc[BC];
#pragma unroll
  for (int c = 0; c < BC; ++c) {
    int cb = (wave * BC + c) * 64 + lane;
    int row = cb >> 3, slot = cb & 7;
    int sc = slot ^ (row & 7);
    bSrc[c] = WT + ((size_t)e * N_ + (n0 + row)) * (size_t)K_ + sc * 8;
  }

  auto STAGE = [&](int kt, unsigned short* Asb, unsigned short* Bsb) {
#pragma unroll
    for (int c = 0; c < AC; ++c)
      load_lds16(aSrc[c] + kt, Asb + (wave * AC + c) * 512);
#pragma unroll
    for (int c = 0; c < BC; ++c)
      load_lds16(bSrc[c] + kt, Bsb + (wave * BC + c) * 512);
  };

  fx4 acc[FM][FN];
#pragma unroll
  for (int a = 0; a < FM; ++a)
#pragma unroll
    for (int b = 0; b < FN; ++b) acc[a][b] = (fx4){0.f, 0.f, 0.f, 0.f};

  auto COMPUTE = [&](const unsigned short* Asb, const unsigned short* Bsb) {
    __builtin_amdgcn_s_setprio(1);
#pragma unroll
    for (int kk = 0; kk < 2; ++kk) {
      bfx8 af[FM], bf[FN];
#pragma unroll
      for (int fm = 0; fm < FM; ++fm) {
        int r = wm * (BM / 2) + fm * 16 + (lane & 15);
        int c = (kk * 4 + (lane >> 4)) ^ (r & 7);
        af[fm] = *(const bfx8*)(Asb + r * 64 + c * 8);
      }
#pragma unroll
      for (int fn = 0; fn < FN; ++fn) {
        int nn = wn * (BN / 2) + fn * 16 + (lane & 15);
        int c = (kk * 4 + (lane >> 4)) ^ (nn & 7);
        bf[fn] = *(const bfx8*)(Bsb + nn * 64 + c * 8);
      }
#pragma unroll
      for (int fm = 0; fm < FM; ++fm)
#pragma unroll
        for (int fn = 0; fn < FN; ++fn)
          acc[fm][fn] = __builtin_amdgcn_mfma_f32_16x16x32_bf16(
              af[fm], bf[fn], acc[fm][fn], 0, 0, 0);
    }
    __builtin_amdgcn_s_setprio(0);
  };

  // ---- prologue ----
  STAGE(0, As[0], Bs[0]);
  __syncthreads();

  // ---- main loop: 2-phase, double-buffered, __syncthreads per K-step ----
#pragma unroll 2
  for (int t = 0; t < NT; ++t) {
    const int c = t & 1;
    if (t + 1 < NT) STAGE((t + 1) * BK, As[c ^ 1], Bs[c ^ 1]);
    COMPUTE(As[c], Bs[c]);
    __syncthreads();
  }

  // ---- epilogue ----
  const int colbase = n0 + wn * (BN / 2);
  if (FIRST) {
#pragma unroll
    for (int fn = 0; fn < FN; ++fn) {
      int colg = colbase + fn * 16 + (lane & 15);
      float bv = Bias[(size_t)e * N_ + colg];
#pragma unroll
      for (int fm = 0; fm < FM; ++fm) {
        int rg = rowbase + wm * (BM / 2) + fm * 16 + ((lane >> 4) << 2);
#pragma unroll
        for (int j = 0; j < 4; ++j) {
          float v = fmaxf(acc[fm][fn][j] + bv, 0.f);
          Hout[(size_t)(rg + j) * N_ + colg] = f2bf(v);
        }
      }
    }
  } else {
#pragma unroll
    for (int fm = 0; fm < FM; ++fm) {
      int rg = rowbase + wm * (BM / 2) + fm * 16 + ((lane >> 4) << 2);
#pragma unroll
      for (int j = 0; j < 4; ++j) {
        int tok = perm_out[rg + j];
        if (tok < 0) continue;
        float pm = pmax[tok];
#pragma unroll
        for (int fn = 0; fn < FN; ++fn) {
          int colg = colbase + fn * 16 + (lane & 15);
          Out[(size_t)tok * N_ + colg] = (acc[fm][fn][j] + Bias[(size_t)e * N_ + colg]) * pm;
        }
      }
    }
  }
}

extern "C" void kernel_launch(void* const* d_in, const int* in_sizes, int n_in,
                              void* d_out, int out_size, void* d_ws, size_t ws_size,
                              hipStream_t stream) {
  const float* x  = (const float*)d_in[0];
  const float* sw = (const float*)d_in[1];
  const float* sb = (const float*)d_in[2];
  const float* w1 = (const float*)d_in[3];
  const float* b1 = (const float*)d_in[4];
  const float* w2 = (const float*)d_in[5];
  const float* b2 = (const float*)d_in[6];
  float* out = (float*)d_out;

  char* ws = (char*)d_ws;
  int*   off      = (int*)(ws + 0);          // 9 ints
  int*   routes   = (int*)(ws + 1024);       // 2048 ints
  int*   perm_out = (int*)(ws + 16384);      // RPMAX ints (pads -1)
  int*   perm_src = (int*)(ws + 32768);      // RPMAX ints (pads 0)
  float* probs    = (float*)(ws + 49152);    // 2048x8 fp32
  unsigned short* xbf = (unsigned short*)(ws + (1u << 20));    // 4 MB
  unsigned short* H   = (unsigned short*)(ws + (8u << 20));    // 24 MB
  unsigned short* WT1 = (unsigned short*)(ws + (40u << 20));   // 64 MB [E][F][D]
  unsigned short* WT2 = (unsigned short*)(ws + (112u << 20));  // 64 MB [E][D][F]

  // d_out layout: final(2097152) | counts(8) | psums(8) | 0(1) | pmax(2048)
  float* out_final  = out;
  float* out_counts = out + 2097152;
  float* out_psums  = out + 2097160;
  float* out_zero   = out + 2097168;
  float* out_pmax   = out + 2097169;

  router_kernel<<<T_TOK / 4, 256, 0, stream>>>(x, sw, sb, out_pmax, routes, probs, xbf);
  plan_kernel<<<1, 256, 0, stream>>>(routes, probs, off, perm_out, perm_src,
                                     out_counts, out_psums, out_zero);

  // weight convert+transpose fp32 [K][N] -> bf16 [N][K]
  conv_kernel<D_DIM, F_DIM><<<dim3(F_DIM / 32, D_DIM / 64, E_NUM), 256, 0, stream>>>(w1, WT1);
  conv_kernel<F_DIM, D_DIM><<<dim3(D_DIM / 32, F_DIM / 64, E_NUM), 256, 0, stream>>>(w2, WT2);

  // GEMM1: gather(xbf)[RP,1024] x WT1^T -> H (relu, bf16). 128x128, grid 32x24=768.
  gemm2ph<128, 128, D_DIM, F_DIM, true, true>
      <<<dim3(F_DIM / 128, RPMAX / 128), 256, 0, stream>>>(
          xbf, WT1, b1, off, perm_src, perm_out, nullptr, H, nullptr);
  // GEMM2: H[RP,4096] x WT2^T -> out (bias, *pmax, scatter). 128x64, grid 16x24=384.
  gemm2ph<128, 64, F_DIM, D_DIM, false, false>
      <<<dim3(D_DIM / 64, RPMAX / 128), 256, 0, stream>>>(
          H, WT2, b2, off, perm_src, perm_out, out_pmax, nullptr, out_final);
}

// Round 12
// 196.978 us; speedup vs baseline: 1.0906x; 1.0906x over previous
//
#include <hip/hip_runtime.h>
#include <stdint.h>

// Problem constants (B=2,S=1024,D=1024,F=4096,E=8)
#define T_TOK 2048
#define D_DIM 1024
#define F_DIM 4096
#define E_NUM 8
#define RPMAX 3072   // max padded rows: sum of per-expert ceil(cnt,128)
#define BK 64

typedef __attribute__((ext_vector_type(8))) short bfx8;   // 8 bf16 (4 VGPR)
typedef __attribute__((ext_vector_type(4))) float fx4;    // MFMA accum

__device__ __forceinline__ unsigned short f2bf(float f) {
  union { float f; uint32_t u; } v; v.f = f;
  uint32_t u = v.u;
  u += 0x7FFFu + ((u >> 16) & 1u);   // round-to-nearest-even
  return (unsigned short)(u >> 16);
}

__device__ __forceinline__ void load_lds16(const unsigned short* g, unsigned short* l) {
  __builtin_amdgcn_global_load_lds(
      (const __attribute__((address_space(1))) void*)g,
      (__attribute__((address_space(3))) void*)l, 16, 0, 0);
}

// ---------------- router: logits, softmax, argmax; NO global atomics ----------------
__global__ __launch_bounds__(256) void router_kernel(
    const float* __restrict__ x, const float* __restrict__ sw,
    const float* __restrict__ sb, float* __restrict__ pmax_out,
    int* __restrict__ routes, float* __restrict__ probs,
    unsigned short* __restrict__ xbf) {
  const int wave = threadIdx.x >> 6, lane = threadIdx.x & 63;
  const int t = blockIdx.x * 4 + wave;
  const float* xr = x + (size_t)t * D_DIM;
  float acc[8];
#pragma unroll
  for (int e = 0; e < 8; ++e) acc[e] = 0.f;
#pragma unroll
  for (int i = 0; i < 4; ++i) {
    const int d = i * 256 + lane * 4;
    float4 xv = *(const float4*)(xr + d);
    ushort4 h;
    h.x = f2bf(xv.x); h.y = f2bf(xv.y); h.z = f2bf(xv.z); h.w = f2bf(xv.w);
    *(ushort4*)(xbf + (size_t)t * D_DIM + d) = h;
    const float xs[4] = {xv.x, xv.y, xv.z, xv.w};
#pragma unroll
    for (int j = 0; j < 4; ++j) {
      const float4* swp = (const float4*)(sw + (size_t)(d + j) * 8);
      float4 w0 = swp[0], w1 = swp[1];
      acc[0] += xs[j] * w0.x; acc[1] += xs[j] * w0.y;
      acc[2] += xs[j] * w0.z; acc[3] += xs[j] * w0.w;
      acc[4] += xs[j] * w1.x; acc[5] += xs[j] * w1.y;
      acc[6] += xs[j] * w1.z; acc[7] += xs[j] * w1.w;
    }
  }
#pragma unroll
  for (int e = 0; e < 8; ++e) {
    float v = acc[e];
    for (int o = 32; o > 0; o >>= 1) v += __shfl_down(v, o, 64);
    acc[e] = v;
  }
  if (lane == 0) {
#pragma unroll
    for (int e = 0; e < 8; ++e) acc[e] += sb[e];
    int am = 0; float mx = acc[0];
#pragma unroll
    for (int e = 1; e < 8; ++e) if (acc[e] > mx) { mx = acc[e]; am = e; }  // first-max wins
    float p[8]; float s = 0.f;
#pragma unroll
    for (int e = 0; e < 8; ++e) { p[e] = expf(acc[e] - mx); s += p[e]; }
    float inv = 1.0f / s;
    pmax_out[t] = inv;
    routes[t] = am;
#pragma unroll
    for (int e = 0; e < 8; ++e) probs[(size_t)t * 8 + e] = p[e] * inv;
  }
}

// -------- plan: counts/psums reduce, offsets, perm init, scatter (fused) --------
__global__ __launch_bounds__(256) void plan_kernel(
    const int* __restrict__ routes, const float* __restrict__ probs,
    int* __restrict__ off, int* __restrict__ perm_out, int* __restrict__ perm_src,
    float* __restrict__ out_counts, float* __restrict__ out_psums,
    float* __restrict__ out_zero) {
  __shared__ int cnt[8];
  __shared__ int cur[8];
  __shared__ int offs[9];
  __shared__ float red[256][8];
  const int tid = threadIdx.x;
  if (tid < 8) cnt[tid] = 0;
  for (int i = tid; i < RPMAX; i += 256) { perm_out[i] = -1; perm_src[i] = 0; }
  __syncthreads();
  float loc[8];
#pragma unroll
  for (int e = 0; e < 8; ++e) loc[e] = 0.f;
  for (int t = tid; t < T_TOK; t += 256) {
    atomicAdd(&cnt[routes[t]], 1);
    const float4* p = (const float4*)(probs + (size_t)t * 8);
    float4 a = p[0], b = p[1];
    loc[0] += a.x; loc[1] += a.y; loc[2] += a.z; loc[3] += a.w;
    loc[4] += b.x; loc[5] += b.y; loc[6] += b.z; loc[7] += b.w;
  }
#pragma unroll
  for (int e = 0; e < 8; ++e) red[tid][e] = loc[e];
  __syncthreads();
  for (int s = 128; s >= 1; s >>= 1) {
    if (tid < s) {
#pragma unroll
      for (int e = 0; e < 8; ++e) red[tid][e] += red[tid + s][e];
    }
    __syncthreads();
  }
  if (tid == 0) {
    int o = 0;
    for (int e = 0; e < 8; ++e) { offs[e] = o; o += ((cnt[e] + 127) >> 7) << 7; }
    offs[8] = o;
    *out_zero = 0.0f;
  }
  __syncthreads();
  if (tid < 9) off[tid] = offs[tid];
  if (tid < 8) {
    cur[tid] = offs[tid];
    out_counts[tid] = (float)cnt[tid];
    out_psums[tid] = red[0][tid];
  }
  __syncthreads();
  for (int t = tid; t < T_TOK; t += 256) {
    int e = routes[t];
    int pos = atomicAdd(&cur[e], 1);
    perm_out[pos] = t;
    perm_src[pos] = t;
  }
}

// ---------------- convert+transpose: W fp32 [E][K][N] -> bf16 [E][N][K] ----------------
template <int K_, int N_>
__global__ __launch_bounds__(256) void conv_kernel(
    const float* __restrict__ W, unsigned short* __restrict__ WT) {
  __shared__ unsigned short tile[64][34];   // [k][n], pad to 34 u16
  const int t = threadIdx.x;
  const int nbase = blockIdx.x * 32;
  const int kbase = blockIdx.y * 64;
  const int e = blockIdx.z;
  const float* We = W + (size_t)e * K_ * N_;
  unsigned short* WTe = WT + (size_t)e * N_ * K_;
  {
    int kl = t >> 2;               // 0..63
    int nc = (t & 3) * 8;          // 0..24 step 8
    const float4* src = (const float4*)(We + (size_t)(kbase + kl) * N_ + nbase + nc);
    float4 a = src[0], b = src[1];
    unsigned short u[8] = {f2bf(a.x), f2bf(a.y), f2bf(a.z), f2bf(a.w),
                           f2bf(b.x), f2bf(b.y), f2bf(b.z), f2bf(b.w)};
#pragma unroll
    for (int p = 0; p < 4; ++p) {
      uint32_t pk = (uint32_t)u[2 * p] | ((uint32_t)u[2 * p + 1] << 16);
      *(uint32_t*)&tile[kl][nc + 2 * p] = pk;
    }
  }
  __syncthreads();
  {
    int nl = t >> 3;               // 0..31
    int kc = (t & 7) * 8;          // 0..56 step 8
    bfx8 v;
#pragma unroll
    for (int i = 0; i < 8; ++i) v[i] = (short)tile[kc + i][nl];
    *(bfx8*)(WTe + (size_t)(nbase + nl) * K_ + kbase + kc) = v;
  }
}

// ---------------- grouped GEMM, m97-exact single-buffer 2-barrier ----------------
// BMxBN tile, BK=64, 4 waves (2m x 2n). BOTH operands bf16 via global_load_lds
// (pre-swizzled per-lane source, key row&7; LDS linear). SINGLE buffer, small LDS
// (32/24 KB) -> 5-6 blocks/CU fit; cross-block TLP hides the stage drain (m114).
// Per K-step: STAGE(t) -> __syncthreads -> COMPUTE(t) -> __syncthreads.
// n-chunked XCD swizzle: each XCD owns contiguous col-panels (weights L2-resident).
// KSPLIT>1: split-K over blockIdx.z; epilogue atomicAdd into zeroed Out.
template <int BM, int BN, int K_, int N_, int KSPLIT, bool FIRST>
__global__ __launch_bounds__(256, 4) void gemm1b(
    const unsigned short* __restrict__ A,    // FIRST: xbf [T][K_]; else H [RP][K_]
    const unsigned short* __restrict__ WT,   // [E][N_][K_] bf16
    const float* __restrict__ Bias,          // [E][N_]
    const int* __restrict__ off,
    const int* __restrict__ perm_src, const int* __restrict__ perm_out,
    const float* __restrict__ pmax,
    unsigned short* __restrict__ Hout, float* __restrict__ Out) {
  constexpr int KS = K_ / KSPLIT;             // K per slice
  constexpr int NT = KS / BK;
  constexpr int FM = BM / 32, FN = BN / 32;   // frags per wave
  constexpr int AC = BM / 32, BC = BN / 32;   // DMA instrs per wave
  constexpr int NBX = N_ / BN;
  __shared__ __align__(16) unsigned short As[BM * 64];
  __shared__ __align__(16) unsigned short Bs[BN * 64];
  const int tid = threadIdx.x;
  const int nby = gridDim.y;
  // placement-linear id (x fastest) -> XCD = lin & 7 (round-robin dispatch)
  const int lin = (blockIdx.z * nby + blockIdx.y) * NBX + blockIdx.x;
  const int total = NBX * nby * KSPLIT;
  const int chunkg = total >> 3;
  const int newlin = (lin & 7) * chunkg + (lin >> 3);
  // n-chunked decomposition: col-panel major -> each XCD owns contiguous bx range
  const int bx = newlin / (nby * KSPLIT);
  const int rem = newlin % (nby * KSPLIT);
  const int by = rem % nby;
  const int kz = rem / nby;
  const int rowbase = by * BM;
  if (rowbase >= off[8]) return;
  int e = 0;
#pragma unroll
  for (int i = 1; i <= 7; ++i) if (rowbase >= off[i]) e = i;
  const int n0 = bx * BN;
  const int k0base = kz * KS;
  const int wave = tid >> 6, lane = tid & 63;
  const int wm = wave >> 1, wn = wave & 1;

  // per-lane pre-swizzled global sources (m173): LDS linear, src chunk XOR'd
  const unsigned short* aSrc[AC];
#pragma unroll
  for (int c = 0; c < AC; ++c) {
    int ca = (wave * AC + c) * 64 + lane;
    int row = ca >> 3, slot = ca & 7;
    int sc = slot ^ (row & 7);
    size_t arow = FIRST ? (size_t)perm_src[rowbase + row] : (size_t)(rowbase + row);
    aSrc[c] = A + arow * K_ + k0base + sc * 8;
  }
  const unsigned short* bSrc[BC];
#pragma unroll
  for (int c = 0; c < BC; ++c) {
    int cb = (wave * BC + c) * 64 + lane;
    int row = cb >> 3, slot = cb & 7;
    int sc = slot ^ (row & 7);
    bSrc[c] = WT + ((size_t)e * N_ + (n0 + row)) * (size_t)K_ + k0base + sc * 8;
  }

  fx4 acc[FM][FN];
#pragma unroll
  for (int a = 0; a < FM; ++a)
#pragma unroll
    for (int b = 0; b < FN; ++b) acc[a][b] = (fx4){0.f, 0.f, 0.f, 0.f};

  // ---- main loop: m97 structure ----
  for (int t = 0; t < NT; ++t) {
    const int kt = t * BK;
#pragma unroll
    for (int c = 0; c < AC; ++c)
      load_lds16(aSrc[c] + kt, As + (wave * AC + c) * 512);
#pragma unroll
    for (int c = 0; c < BC; ++c)
      load_lds16(bSrc[c] + kt, Bs + (wave * BC + c) * 512);
    __syncthreads();
#pragma unroll
    for (int kk = 0; kk < 2; ++kk) {
      bfx8 af[FM], bf[FN];
#pragma unroll
      for (int fm = 0; fm < FM; ++fm) {
        int r = wm * (BM / 2) + fm * 16 + (lane & 15);
        int c = (kk * 4 + (lane >> 4)) ^ (r & 7);
        af[fm] = *(const bfx8*)(As + r * 64 + c * 8);
      }
#pragma unroll
      for (int fn = 0; fn < FN; ++fn) {
        int nn = wn * (BN / 2) + fn * 16 + (lane & 15);
        int c = (kk * 4 + (lane >> 4)) ^ (nn & 7);
        bf[fn] = *(const bfx8*)(Bs + nn * 64 + c * 8);
      }
#pragma unroll
      for (int fm = 0; fm < FM; ++fm)
#pragma unroll
        for (int fn = 0; fn < FN; ++fn)
          acc[fm][fn] = __builtin_amdgcn_mfma_f32_16x16x32_bf16(
              af[fm], bf[fn], acc[fm][fn], 0, 0, 0);
    }
    __syncthreads();
  }

  // ---- epilogue ----
  const int colbase = n0 + wn * (BN / 2);
  if (FIRST) {
#pragma unroll
    for (int fn = 0; fn < FN; ++fn) {
      int colg = colbase + fn * 16 + (lane & 15);
      float bv = Bias[(size_t)e * N_ + colg];
#pragma unroll
      for (int fm = 0; fm < FM; ++fm) {
        int rg = rowbase + wm * (BM / 2) + fm * 16 + ((lane >> 4) << 2);
#pragma unroll
        for (int j = 0; j < 4; ++j) {
          float v = fmaxf(acc[fm][fn][j] + bv, 0.f);
          Hout[(size_t)(rg + j) * N_ + colg] = f2bf(v);
        }
      }
    }
  } else {
#pragma unroll
    for (int fm = 0; fm < FM; ++fm) {
      int rg = rowbase + wm * (BM / 2) + fm * 16 + ((lane >> 4) << 2);
#pragma unroll
      for (int j = 0; j < 4; ++j) {
        int tok = perm_out[rg + j];
        if (tok < 0) continue;
        float pm = pmax[tok];
#pragma unroll
        for (int fn = 0; fn < FN; ++fn) {
          int colg = colbase + fn * 16 + (lane & 15);
          float v = acc[fm][fn][j];
          if (kz == 0) v += Bias[(size_t)e * N_ + colg];
          atomicAdd(&Out[(size_t)tok * N_ + colg], v * pm);
        }
      }
    }
  }
}

extern "C" void kernel_launch(void* const* d_in, const int* in_sizes, int n_in,
                              void* d_out, int out_size, void* d_ws, size_t ws_size,
                              hipStream_t stream) {
  const float* x  = (const float*)d_in[0];
  const float* sw = (const float*)d_in[1];
  const float* sb = (const float*)d_in[2];
  const float* w1 = (const float*)d_in[3];
  const float* b1 = (const float*)d_in[4];
  const float* w2 = (const float*)d_in[5];
  const float* b2 = (const float*)d_in[6];
  float* out = (float*)d_out;

  char* ws = (char*)d_ws;
  int*   off      = (int*)(ws + 0);          // 9 ints
  int*   routes   = (int*)(ws + 1024);       // 2048 ints
  int*   perm_out = (int*)(ws + 16384);      // RPMAX ints (pads -1)
  int*   perm_src = (int*)(ws + 32768);      // RPMAX ints (pads 0)
  float* probs    = (float*)(ws + 49152);    // 2048x8 fp32
  unsigned short* xbf = (unsigned short*)(ws + (1u << 20));    // 4 MB
  unsigned short* H   = (unsigned short*)(ws + (8u << 20));    // 24 MB
  unsigned short* WT1 = (unsigned short*)(ws + (40u << 20));   // 64 MB [E][F][D]
  unsigned short* WT2 = (unsigned short*)(ws + (112u << 20));  // 64 MB [E][D][F]

  // d_out layout: final(2097152) | counts(8) | psums(8) | 0(1) | pmax(2048)
  float* out_final  = out;
  float* out_counts = out + 2097152;
  float* out_psums  = out + 2097160;
  float* out_zero   = out + 2097168;
  float* out_pmax   = out + 2097169;

  // split-K GEMM2 accumulates atomically into out_final -> zero it each call
  hipMemsetAsync(out_final, 0, 2097152 * sizeof(float), stream);

  router_kernel<<<T_TOK / 4, 256, 0, stream>>>(x, sw, sb, out_pmax, routes, probs, xbf);
  plan_kernel<<<1, 256, 0, stream>>>(routes, probs, off, perm_out, perm_src,
                                     out_counts, out_psums, out_zero);

  // weight convert+transpose fp32 [K][N] -> bf16 [N][K]
  conv_kernel<D_DIM, F_DIM><<<dim3(F_DIM / 32, D_DIM / 64, E_NUM), 256, 0, stream>>>(w1, WT1);
  conv_kernel<F_DIM, D_DIM><<<dim3(D_DIM / 32, F_DIM / 64, E_NUM), 256, 0, stream>>>(w2, WT2);

  // GEMM1: gather(xbf)[RP,1024] x WT1^T -> H (relu, bf16). 128x128, 32KB LDS,
  // grid 32x24=768 (3/CU, 5 fit), n-chunked.
  gemm1b<128, 128, D_DIM, F_DIM, 1, true>
      <<<dim3(F_DIM / 128, RPMAX / 128, 1), 256, 0, stream>>>(
          xbf, WT1, b1, off, perm_src, perm_out, nullptr, H, nullptr);
  // GEMM2: H[RP,4096] x WT2^T -> out (bias, *pmax, scatter, atomic split-K=2).
  // 128x64, 24KB LDS, grid 16x24x2=768 (3/CU, 6 fit), n-chunked.
  gemm1b<128, 64, F_DIM, D_DIM, 2, false>
      <<<dim3(D_DIM / 64, RPMAX / 128, 2), 256, 0, stream>>>(
          H, WT2, b2, off, perm_src, perm_out, out_pmax, nullptr, out_final);
}

// Round 13
// 196.007 us; speedup vs baseline: 1.0960x; 1.0050x over previous
//
#include <hip/hip_runtime.h>
#include <stdint.h>

// Problem constants (B=2,S=1024,D=1024,F=4096,E=8)
#define T_TOK 2048
#define D_DIM 1024
#define F_DIM 4096
#define E_NUM 8
#define RPMAX 3072   // max padded rows: sum of per-expert ceil(cnt,128)
#define BK 64

typedef __attribute__((ext_vector_type(8))) short bfx8;   // 8 bf16 (4 VGPR)
typedef __attribute__((ext_vector_type(4))) float fx4;    // MFMA accum

__device__ __forceinline__ unsigned short f2bf(float f) {
  union { float f; uint32_t u; } v; v.f = f;
  uint32_t u = v.u;
  u += 0x7FFFu + ((u >> 16) & 1u);   // round-to-nearest-even
  return (unsigned short)(u >> 16);
}

__device__ __forceinline__ void load_lds16(const unsigned short* g, unsigned short* l) {
  __builtin_amdgcn_global_load_lds(
      (const __attribute__((address_space(1))) void*)g,
      (__attribute__((address_space(3))) void*)l, 16, 0, 0);
}

// ---------------- fast zero: 8 MB in ~2 us (rocclr fill is ~75 us here) ----------------
__global__ __launch_bounds__(256) void zero_kernel(float4* __restrict__ p) {
  p[(size_t)blockIdx.x * 256 + threadIdx.x] = make_float4(0.f, 0.f, 0.f, 0.f);
}

// ---------------- router: logits, softmax, argmax; NO global atomics ----------------
__global__ __launch_bounds__(256) void router_kernel(
    const float* __restrict__ x, const float* __restrict__ sw,
    const float* __restrict__ sb, float* __restrict__ pmax_out,
    int* __restrict__ routes, float* __restrict__ probs,
    unsigned short* __restrict__ xbf) {
  const int wave = threadIdx.x >> 6, lane = threadIdx.x & 63;
  const int t = blockIdx.x * 4 + wave;
  const float* xr = x + (size_t)t * D_DIM;
  float acc[8];
#pragma unroll
  for (int e = 0; e < 8; ++e) acc[e] = 0.f;
#pragma unroll
  for (int i = 0; i < 4; ++i) {
    const int d = i * 256 + lane * 4;
    float4 xv = *(const float4*)(xr + d);
    ushort4 h;
    h.x = f2bf(xv.x); h.y = f2bf(xv.y); h.z = f2bf(xv.z); h.w = f2bf(xv.w);
    *(ushort4*)(xbf + (size_t)t * D_DIM + d) = h;
    const float xs[4] = {xv.x, xv.y, xv.z, xv.w};
#pragma unroll
    for (int j = 0; j < 4; ++j) {
      const float4* swp = (const float4*)(sw + (size_t)(d + j) * 8);
      float4 w0 = swp[0], w1 = swp[1];
      acc[0] += xs[j] * w0.x; acc[1] += xs[j] * w0.y;
      acc[2] += xs[j] * w0.z; acc[3] += xs[j] * w0.w;
      acc[4] += xs[j] * w1.x; acc[5] += xs[j] * w1.y;
      acc[6] += xs[j] * w1.z; acc[7] += xs[j] * w1.w;
    }
  }
#pragma unroll
  for (int e = 0; e < 8; ++e) {
    float v = acc[e];
    for (int o = 32; o > 0; o >>= 1) v += __shfl_down(v, o, 64);
    acc[e] = v;
  }
  if (lane == 0) {
#pragma unroll
    for (int e = 0; e < 8; ++e) acc[e] += sb[e];
    int am = 0; float mx = acc[0];
#pragma unroll
    for (int e = 1; e < 8; ++e) if (acc[e] > mx) { mx = acc[e]; am = e; }  // first-max wins
    float p[8]; float s = 0.f;
#pragma unroll
    for (int e = 0; e < 8; ++e) { p[e] = expf(acc[e] - mx); s += p[e]; }
    float inv = 1.0f / s;
    pmax_out[t] = inv;
    routes[t] = am;
#pragma unroll
    for (int e = 0; e < 8; ++e) probs[(size_t)t * 8 + e] = p[e] * inv;
  }
}

// -------- plan: counts/psums reduce, offsets, perm init, scatter (fused) --------
__global__ __launch_bounds__(256) void plan_kernel(
    const int* __restrict__ routes, const float* __restrict__ probs,
    int* __restrict__ off, int* __restrict__ perm_out, int* __restrict__ perm_src,
    float* __restrict__ out_counts, float* __restrict__ out_psums,
    float* __restrict__ out_zero) {
  __shared__ int cnt[8];
  __shared__ int cur[8];
  __shared__ int offs[9];
  __shared__ float red[256][8];
  const int tid = threadIdx.x;
  if (tid < 8) cnt[tid] = 0;
  for (int i = tid; i < RPMAX; i += 256) { perm_out[i] = -1; perm_src[i] = 0; }
  __syncthreads();
  float loc[8];
#pragma unroll
  for (int e = 0; e < 8; ++e) loc[e] = 0.f;
  for (int t = tid; t < T_TOK; t += 256) {
    atomicAdd(&cnt[routes[t]], 1);
    const float4* p = (const float4*)(probs + (size_t)t * 8);
    float4 a = p[0], b = p[1];
    loc[0] += a.x; loc[1] += a.y; loc[2] += a.z; loc[3] += a.w;
    loc[4] += b.x; loc[5] += b.y; loc[6] += b.z; loc[7] += b.w;
  }
#pragma unroll
  for (int e = 0; e < 8; ++e) red[tid][e] = loc[e];
  __syncthreads();
  for (int s = 128; s >= 1; s >>= 1) {
    if (tid < s) {
#pragma unroll
      for (int e = 0; e < 8; ++e) red[tid][e] += red[tid + s][e];
    }
    __syncthreads();
  }
  if (tid == 0) {
    int o = 0;
    for (int e = 0; e < 8; ++e) { offs[e] = o; o += ((cnt[e] + 127) >> 7) << 7; }
    offs[8] = o;
    *out_zero = 0.0f;
  }
  __syncthreads();
  if (tid < 9) off[tid] = offs[tid];
  if (tid < 8) {
    cur[tid] = offs[tid];
    out_counts[tid] = (float)cnt[tid];
    out_psums[tid] = red[0][tid];
  }
  __syncthreads();
  for (int t = tid; t < T_TOK; t += 256) {
    int e = routes[t];
    int pos = atomicAdd(&cur[e], 1);
    perm_out[pos] = t;
    perm_src[pos] = t;
  }
}

// ---------------- convert+transpose: W fp32 [E][K][N] -> bf16 [E][N][K] ----------------
template <int K_, int N_>
__global__ __launch_bounds__(256) void conv_kernel(
    const float* __restrict__ W, unsigned short* __restrict__ WT) {
  __shared__ unsigned short tile[64][34];   // [k][n], pad to 34 u16
  const int t = threadIdx.x;
  const int nbase = blockIdx.x * 32;
  const int kbase = blockIdx.y * 64;
  const int e = blockIdx.z;
  const float* We = W + (size_t)e * K_ * N_;
  unsigned short* WTe = WT + (size_t)e * N_ * K_;
  {
    int kl = t >> 2;               // 0..63
    int nc = (t & 3) * 8;          // 0..24 step 8
    const float4* src = (const float4*)(We + (size_t)(kbase + kl) * N_ + nbase + nc);
    float4 a = src[0], b = src[1];
    unsigned short u[8] = {f2bf(a.x), f2bf(a.y), f2bf(a.z), f2bf(a.w),
                           f2bf(b.x), f2bf(b.y), f2bf(b.z), f2bf(b.w)};
#pragma unroll
    for (int p = 0; p < 4; ++p) {
      uint32_t pk = (uint32_t)u[2 * p] | ((uint32_t)u[2 * p + 1] << 16);
      *(uint32_t*)&tile[kl][nc + 2 * p] = pk;
    }
  }
  __syncthreads();
  {
    int nl = t >> 3;               // 0..31
    int kc = (t & 7) * 8;          // 0..56 step 8
    bfx8 v;
#pragma unroll
    for (int i = 0; i < 8; ++i) v[i] = (short)tile[kc + i][nl];
    *(bfx8*)(WTe + (size_t)(nbase + nl) * K_ + kbase + kc) = v;
  }
}

// ---------------- grouped GEMM, m97-exact single-buffer 2-barrier ----------------
// BMxBN tile, BK=64, 4 waves (2m x 2n). BOTH operands bf16 via global_load_lds
// (pre-swizzled per-lane source, key row&7; LDS linear). SINGLE buffer, small LDS
// (32/24 KB) -> 5-6 blocks/CU fit; cross-block TLP hides the stage drain (m114).
// Per K-step: STAGE(t) -> __syncthreads -> COMPUTE(t) -> __syncthreads.
// n-chunked XCD swizzle: each XCD owns contiguous col-panels (weights L2-resident).
// KSPLIT>1: split-K over blockIdx.z; epilogue atomicAdd into zeroed Out.
template <int BM, int BN, int K_, int N_, int KSPLIT, bool FIRST>
__global__ __launch_bounds__(256, 4) void gemm1b(
    const unsigned short* __restrict__ A,    // FIRST: xbf [T][K_]; else H [RP][K_]
    const unsigned short* __restrict__ WT,   // [E][N_][K_] bf16
    const float* __restrict__ Bias,          // [E][N_]
    const int* __restrict__ off,
    const int* __restrict__ perm_src, const int* __restrict__ perm_out,
    const float* __restrict__ pmax,
    unsigned short* __restrict__ Hout, float* __restrict__ Out) {
  constexpr int KS = K_ / KSPLIT;             // K per slice
  constexpr int NT = KS / BK;
  constexpr int FM = BM / 32, FN = BN / 32;   // frags per wave
  constexpr int AC = BM / 32, BC = BN / 32;   // DMA instrs per wave
  constexpr int NBX = N_ / BN;
  __shared__ __align__(16) unsigned short As[BM * 64];
  __shared__ __align__(16) unsigned short Bs[BN * 64];
  const int tid = threadIdx.x;
  const int nby = gridDim.y;
  // placement-linear id (x fastest) -> XCD = lin & 7 (round-robin dispatch)
  const int lin = (blockIdx.z * nby + blockIdx.y) * NBX + blockIdx.x;
  const int total = NBX * nby * KSPLIT;
  const int chunkg = total >> 3;
  const int newlin = (lin & 7) * chunkg + (lin >> 3);
  // n-chunked decomposition: col-panel major -> each XCD owns contiguous bx range
  const int bx = newlin / (nby * KSPLIT);
  const int rem = newlin % (nby * KSPLIT);
  const int by = rem % nby;
  const int kz = rem / nby;
  const int rowbase = by * BM;
  if (rowbase >= off[8]) return;
  int e = 0;
#pragma unroll
  for (int i = 1; i <= 7; ++i) if (rowbase >= off[i]) e = i;
  const int n0 = bx * BN;
  const int k0base = kz * KS;
  const int wave = tid >> 6, lane = tid & 63;
  const int wm = wave >> 1, wn = wave & 1;

  // per-lane pre-swizzled global sources (m173): LDS linear, src chunk XOR'd
  const unsigned short* aSrc[AC];
#pragma unroll
  for (int c = 0; c < AC; ++c) {
    int ca = (wave * AC + c) * 64 + lane;
    int row = ca >> 3, slot = ca & 7;
    int sc = slot ^ (row & 7);
    size_t arow = FIRST ? (size_t)perm_src[rowbase + row] : (size_t)(rowbase + row);
    aSrc[c] = A + arow * K_ + k0base + sc * 8;
  }
  const unsigned short* bSrc[BC];
#pragma unroll
  for (int c = 0; c < BC; ++c) {
    int cb = (wave * BC + c) * 64 + lane;
    int row = cb >> 3, slot = cb & 7;
    int sc = slot ^ (row & 7);
    bSrc[c] = WT + ((size_t)e * N_ + (n0 + row)) * (size_t)K_ + k0base + sc * 8;
  }

  fx4 acc[FM][FN];
#pragma unroll
  for (int a = 0; a < FM; ++a)
#pragma unroll
    for (int b = 0; b < FN; ++b) acc[a][b] = (fx4){0.f, 0.f, 0.f, 0.f};

  // ---- main loop: m97 structure ----
  for (int t = 0; t < NT; ++t) {
    const int kt = t * BK;
#pragma unroll
    for (int c = 0; c < AC; ++c)
      load_lds16(aSrc[c] + kt, As + (wave * AC + c) * 512);
#pragma unroll
    for (int c = 0; c < BC; ++c)
      load_lds16(bSrc[c] + kt, Bs + (wave * BC + c) * 512);
    __syncthreads();
#pragma unroll
    for (int kk = 0; kk < 2; ++kk) {
      bfx8 af[FM], bf[FN];
#pragma unroll
      for (int fm = 0; fm < FM; ++fm) {
        int r = wm * (BM / 2) + fm * 16 + (lane & 15);
        int c = (kk * 4 + (lane >> 4)) ^ (r & 7);
        af[fm] = *(const bfx8*)(As + r * 64 + c * 8);
      }
#pragma unroll
      for (int fn = 0; fn < FN; ++fn) {
        int nn = wn * (BN / 2) + fn * 16 + (lane & 15);
        int c = (kk * 4 + (lane >> 4)) ^ (nn & 7);
        bf[fn] = *(const bfx8*)(Bs + nn * 64 + c * 8);
      }
#pragma unroll
      for (int fm = 0; fm < FM; ++fm)
#pragma unroll
        for (int fn = 0; fn < FN; ++fn)
          acc[fm][fn] = __builtin_amdgcn_mfma_f32_16x16x32_bf16(
              af[fm], bf[fn], acc[fm][fn], 0, 0, 0);
    }
    __syncthreads();
  }

  // ---- epilogue ----
  const int colbase = n0 + wn * (BN / 2);
  if (FIRST) {
#pragma unroll
    for (int fn = 0; fn < FN; ++fn) {
      int colg = colbase + fn * 16 + (lane & 15);
      float bv = Bias[(size_t)e * N_ + colg];
#pragma unroll
      for (int fm = 0; fm < FM; ++fm) {
        int rg = rowbase + wm * (BM / 2) + fm * 16 + ((lane >> 4) << 2);
#pragma unroll
        for (int j = 0; j < 4; ++j) {
          float v = fmaxf(acc[fm][fn][j] + bv, 0.f);
          Hout[(size_t)(rg + j) * N_ + colg] = f2bf(v);
        }
      }
    }
  } else {
#pragma unroll
    for (int fm = 0; fm < FM; ++fm) {
      int rg = rowbase + wm * (BM / 2) + fm * 16 + ((lane >> 4) << 2);
#pragma unroll
      for (int j = 0; j < 4; ++j) {
        int tok = perm_out[rg + j];
        if (tok < 0) continue;
        float pm = pmax[tok];
#pragma unroll
        for (int fn = 0; fn < FN; ++fn) {
          int colg = colbase + fn * 16 + (lane & 15);
          float v = acc[fm][fn][j];
          if (kz == 0) v += Bias[(size_t)e * N_ + colg];
          atomicAdd(&Out[(size_t)tok * N_ + colg], v * pm);
        }
      }
    }
  }
}

extern "C" void kernel_launch(void* const* d_in, const int* in_sizes, int n_in,
                              void* d_out, int out_size, void* d_ws, size_t ws_size,
                              hipStream_t stream) {
  const float* x  = (const float*)d_in[0];
  const float* sw = (const float*)d_in[1];
  const float* sb = (const float*)d_in[2];
  const float* w1 = (const float*)d_in[3];
  const float* b1 = (const float*)d_in[4];
  const float* w2 = (const float*)d_in[5];
  const float* b2 = (const float*)d_in[6];
  float* out = (float*)d_out;

  char* ws = (char*)d_ws;
  int*   off      = (int*)(ws + 0);          // 9 ints
  int*   routes   = (int*)(ws + 1024);       // 2048 ints
  int*   perm_out = (int*)(ws + 16384);      // RPMAX ints (pads -1)
  int*   perm_src = (int*)(ws + 32768);      // RPMAX ints (pads 0)
  float* probs    = (float*)(ws + 49152);    // 2048x8 fp32
  unsigned short* xbf = (unsigned short*)(ws + (1u << 20));    // 4 MB
  unsigned short* H   = (unsigned short*)(ws + (8u << 20));    // 24 MB
  unsigned short* WT1 = (unsigned short*)(ws + (40u << 20));   // 64 MB [E][F][D]
  unsigned short* WT2 = (unsigned short*)(ws + (112u << 20));  // 64 MB [E][D][F]

  // d_out layout: final(2097152) | counts(8) | psums(8) | 0(1) | pmax(2048)
  float* out_final  = out;
  float* out_counts = out + 2097152;
  float* out_psums  = out + 2097160;
  float* out_zero   = out + 2097168;
  float* out_pmax   = out + 2097169;

  // split-K GEMM2 accumulates atomically into out_final -> zero it (custom kernel:
  // rocclr fillBuffer measured 75 us / 111 GB/s for this 8 MB; this runs ~2 us)
  zero_kernel<<<2048, 256, 0, stream>>>((float4*)out_final);

  router_kernel<<<T_TOK / 4, 256, 0, stream>>>(x, sw, sb, out_pmax, routes, probs, xbf);
  plan_kernel<<<1, 256, 0, stream>>>(routes, probs, off, perm_out, perm_src,
                                     out_counts, out_psums, out_zero);

  // weight convert+transpose fp32 [K][N] -> bf16 [N][K]
  conv_kernel<D_DIM, F_DIM><<<dim3(F_DIM / 32, D_DIM / 64, E_NUM), 256, 0, stream>>>(w1, WT1);
  conv_kernel<F_DIM, D_DIM><<<dim3(D_DIM / 32, F_DIM / 64, E_NUM), 256, 0, stream>>>(w2, WT2);

  // GEMM1: gather(xbf)[RP,1024] x WT1^T -> H (relu, bf16). 128x128, 32KB LDS,
  // grid 32x24=768 (3/CU, 5 fit), n-chunked.
  gemm1b<128, 128, D_DIM, F_DIM, 1, true>
      <<<dim3(F_DIM / 128, RPMAX / 128, 1), 256, 0, stream>>>(
          xbf, WT1, b1, off, perm_src, perm_out, nullptr, H, nullptr);
  // GEMM2: H[RP,4096] x WT2^T -> out (bias, *pmax, scatter, atomic split-K=2).
  // 128x64, 24KB LDS, grid 16x24x2=768 (3/CU, 6 fit), n-chunked.
  gemm1b<128, 64, F_DIM, D_DIM, 2, false>
      <<<dim3(D_DIM / 64, RPMAX / 128, 2), 256, 0, stream>>>(
          H, WT2, b2, off, perm_src, perm_out, out_pmax, nullptr, out_final);
}

// Round 14
// 163.777 us; speedup vs baseline: 1.3117x; 1.1968x over previous
//
#include <hip/hip_runtime.h>
#include <stdint.h>

// Problem constants (B=2,S=1024,D=1024,F=4096,E=8)
#define T_TOK 2048
#define D_DIM 1024
#define F_DIM 4096
#define E_NUM 8
#define RPMAX 4096   // max padded rows at 256-alignment: 2048 + 8*255 -> 4096
#define BK 64

typedef __attribute__((ext_vector_type(8))) short bfx8;   // 8 bf16 (4 VGPR)
typedef __attribute__((ext_vector_type(4))) float fx4;    // MFMA accum / staging

__device__ __forceinline__ unsigned short f2bf(float f) {
  union { float f; uint32_t u; } v; v.f = f;
  uint32_t u = v.u;
  u += 0x7FFFu + ((u >> 16) & 1u);   // round-to-nearest-even
  return (unsigned short)(u >> 16);
}

__device__ __forceinline__ void load_lds16(const unsigned short* g, unsigned short* l) {
  __builtin_amdgcn_global_load_lds(
      (const __attribute__((address_space(1))) void*)g,
      (__attribute__((address_space(3))) void*)l, 16, 0, 0);
}

__device__ __forceinline__ uint32_t cvtpk_bf16(float lo, float hi) {
  uint32_t d;
  asm("v_cvt_pk_bf16_f32 %0, %1, %2" : "=v"(d) : "v"(lo), "v"(hi));
  return d;
}

// ---------------- fast zero (rocclr fill is erratic for 8 MB) ----------------
__global__ __launch_bounds__(256) void zero_kernel(float4* __restrict__ p) {
  p[(size_t)blockIdx.x * 256 + threadIdx.x] = make_float4(0.f, 0.f, 0.f, 0.f);
}

// ---------------- router: logits, softmax, argmax; NO global atomics ----------------
__global__ __launch_bounds__(256) void router_kernel(
    const float* __restrict__ x, const float* __restrict__ sw,
    const float* __restrict__ sb, float* __restrict__ pmax_out,
    int* __restrict__ routes, float* __restrict__ probs,
    unsigned short* __restrict__ xbf) {
  const int wave = threadIdx.x >> 6, lane = threadIdx.x & 63;
  const int t = blockIdx.x * 4 + wave;
  const float* xr = x + (size_t)t * D_DIM;
  float acc[8];
#pragma unroll
  for (int e = 0; e < 8; ++e) acc[e] = 0.f;
#pragma unroll
  for (int i = 0; i < 4; ++i) {
    const int d = i * 256 + lane * 4;
    float4 xv = *(const float4*)(xr + d);
    ushort4 h;
    h.x = f2bf(xv.x); h.y = f2bf(xv.y); h.z = f2bf(xv.z); h.w = f2bf(xv.w);
    *(ushort4*)(xbf + (size_t)t * D_DIM + d) = h;
    const float xs[4] = {xv.x, xv.y, xv.z, xv.w};
#pragma unroll
    for (int j = 0; j < 4; ++j) {
      const float4* swp = (const float4*)(sw + (size_t)(d + j) * 8);
      float4 w0 = swp[0], w1 = swp[1];
      acc[0] += xs[j] * w0.x; acc[1] += xs[j] * w0.y;
      acc[2] += xs[j] * w0.z; acc[3] += xs[j] * w0.w;
      acc[4] += xs[j] * w1.x; acc[5] += xs[j] * w1.y;
      acc[6] += xs[j] * w1.z; acc[7] += xs[j] * w1.w;
    }
  }
#pragma unroll
  for (int e = 0; e < 8; ++e) {
    float v = acc[e];
    for (int o = 32; o > 0; o >>= 1) v += __shfl_down(v, o, 64);
    acc[e] = v;
  }
  if (lane == 0) {
#pragma unroll
    for (int e = 0; e < 8; ++e) acc[e] += sb[e];
    int am = 0; float mx = acc[0];
#pragma unroll
    for (int e = 1; e < 8; ++e) if (acc[e] > mx) { mx = acc[e]; am = e; }  // first-max wins
    float p[8]; float s = 0.f;
#pragma unroll
    for (int e = 0; e < 8; ++e) { p[e] = expf(acc[e] - mx); s += p[e]; }
    float inv = 1.0f / s;
    pmax_out[t] = inv;
    routes[t] = am;
#pragma unroll
    for (int e = 0; e < 8; ++e) probs[(size_t)t * 8 + e] = p[e] * inv;
  }
}

// -------- plan: counts/psums reduce, 256-aligned offsets, perm init, scatter --------
__global__ __launch_bounds__(256) void plan_kernel(
    const int* __restrict__ routes, const float* __restrict__ probs,
    int* __restrict__ off, int* __restrict__ perm_out, int* __restrict__ perm_src,
    float* __restrict__ out_counts, float* __restrict__ out_psums,
    float* __restrict__ out_zero) {
  __shared__ int cnt[8];
  __shared__ int cur[8];
  __shared__ int offs[9];
  __shared__ float red[256][8];
  const int tid = threadIdx.x;
  if (tid < 8) cnt[tid] = 0;
  for (int i = tid; i < RPMAX; i += 256) { perm_out[i] = -1; perm_src[i] = 0; }
  __syncthreads();
  float loc[8];
#pragma unroll
  for (int e = 0; e < 8; ++e) loc[e] = 0.f;
  for (int t = tid; t < T_TOK; t += 256) {
    atomicAdd(&cnt[routes[t]], 1);
    const float4* p = (const float4*)(probs + (size_t)t * 8);
    float4 a = p[0], b = p[1];
    loc[0] += a.x; loc[1] += a.y; loc[2] += a.z; loc[3] += a.w;
    loc[4] += b.x; loc[5] += b.y; loc[6] += b.z; loc[7] += b.w;
  }
#pragma unroll
  for (int e = 0; e < 8; ++e) red[tid][e] = loc[e];
  __syncthreads();
  for (int s = 128; s >= 1; s >>= 1) {
    if (tid < s) {
#pragma unroll
      for (int e = 0; e < 8; ++e) red[tid][e] += red[tid + s][e];
    }
    __syncthreads();
  }
  if (tid == 0) {
    int o = 0;
    for (int e = 0; e < 8; ++e) { offs[e] = o; o += ((cnt[e] + 255) >> 8) << 8; }
    offs[8] = o;
    *out_zero = 0.0f;
  }
  __syncthreads();
  if (tid < 9) off[tid] = offs[tid];
  if (tid < 8) {
    cur[tid] = offs[tid];
    out_counts[tid] = (float)cnt[tid];
    out_psums[tid] = red[0][tid];
  }
  __syncthreads();
  for (int t = tid; t < T_TOK; t += 256) {
    int e = routes[t];
    int pos = atomicAdd(&cur[e], 1);
    perm_out[pos] = t;
    perm_src[pos] = t;
  }
}

// ---------------- fused grouped GEMM, 256-class tile, 8 waves, 2-phase ----------------
// BM=256 x BN tile, BK=64, 8 waves (2m x 4n), wave out 128 x BN/4. LDS dbuf:
// A (bf16) via global_load_lds (pre-swizzled src, key row&7, linear LDS);
// B: fp32 W -> float4 reg load (t+1, issued BEFORE compute t) -> cvt_pk bf16 ->
// reg transpose -> swizzled ds_write_b64 (key ((nl>>2)+2(nl&3))&7) AFTER compute.
// Compute phase = 64 MFMA/wave (~1300cy) > HBM latency -> depth-1 covers all.
// __syncthreads only (compiler vmcnt drain; no hand-asm barrier race).
// KSPLIT>1: split-K over bz, atomicAdd epilogue into zeroed Out.
template <int BN, int K_, int N_, int KSPLIT, bool FIRST>
__global__ __launch_bounds__(512, 2) void gemm256(
    const unsigned short* __restrict__ A,    // FIRST: xbf [T][K_]; else H [RP][K_]
    const float* __restrict__ W,             // [E][K_][N_] fp32
    const float* __restrict__ Bias,          // [E][N_]
    const int* __restrict__ off,
    const int* __restrict__ perm_src, const int* __restrict__ perm_out,
    const float* __restrict__ pmax,
    unsigned short* __restrict__ Hout, float* __restrict__ Out) {
  constexpr int BM = 256;
  constexpr int KS = K_ / KSPLIT;
  constexpr int NT = KS / BK;
  constexpr int FM = 8;              // 128/16 rows per wave
  constexpr int FN = BN / 64;        // 4 (BN=256) or 2 (BN=128); wave-N = BN/4
  constexpr int GRP = BN / 128;      // B-staging groups per lane: 2 or 1
  constexpr int NBX = N_ / BN;
  __shared__ __align__(16) unsigned short As[2][BM * 64];
  __shared__ __align__(16) unsigned short Bs[2][BN * 64];
  const int tid = threadIdx.x;
  const int nby = gridDim.y;
  // XCD swizzle, n-chunked: XCD = dispatch-linear & 7; each XCD owns a
  // contiguous bx range so consecutive same-expert by-blocks reuse the
  // 1 MB W panel from its L2.
  const int lin = (blockIdx.z * nby + blockIdx.y) * NBX + blockIdx.x;
  const int total = NBX * nby * KSPLIT;
  const int newlin = (lin & 7) * (total >> 3) + (lin >> 3);
  const int bx = newlin / (nby * KSPLIT);
  const int rem = newlin % (nby * KSPLIT);
  const int by = rem % nby;
  const int kz = rem / nby;
  const int rowbase = by * BM;
  if (rowbase >= off[8]) return;
  int e = 0;
#pragma unroll
  for (int i = 1; i <= 7; ++i) if (rowbase >= off[i]) e = i;
  const int n0 = bx * BN;
  const int k0base = kz * KS;
  const int wave = tid >> 6, lane = tid & 63;
  const int wm = wave >> 2, wn = wave & 3;
  const float* Wn0 = W + (size_t)e * K_ * N_ + n0;

  // A: per-lane pre-swizzled global sources (m173): LDS linear, src chunk XOR'd
  const unsigned short* aSrc[4];
#pragma unroll
  for (int c = 0; c < 4; ++c) {
    int ca = (wave * 4 + c) * 64 + lane;      // 16B-chunk id, 0..2047
    int row = ca >> 3, slot = ca & 7;
    int sc = slot ^ (row & 7);
    size_t arow = FIRST ? (size_t)perm_src[rowbase + row] : (size_t)(rowbase + row);
    aSrc[c] = A + arow * K_ + k0base + sc * 8;
  }

  const int nq = lane & 15;                  // col quad within 64-col block
  const int qg = lane >> 4;                  // 0..3: (k-quad, col-block) selector
  const int kq = (qg & 1) * 4;               // k-quad offset within wave's 8 k-rows
  fx4 br[GRP][4];                            // B staging regs (reloaded every iter)

  auto A_STAGE = [&](int kt, unsigned short* Asb) {
#pragma unroll
    for (int c = 0; c < 4; ++c)
      load_lds16(aSrc[c] + kt, Asb + (wave * 4 + c) * 512);
  };
  auto B_LOAD = [&](int kt) {
#pragma unroll
    for (int g = 0; g < GRP; ++g) {
      const int cb = g * 2 + (qg >> 1);
#pragma unroll
      for (int j = 0; j < 4; ++j)
        br[g][j] = *(const fx4*)(Wn0 + (size_t)(kt + wave * 8 + kq + j) * N_ +
                                 cb * 64 + nq * 4);
    }
  };
  auto B_STORE = [&](unsigned short* Bsb) {
#pragma unroll
    for (int g = 0; g < GRP; ++g) {
      const int cb = g * 2 + (qg >> 1);
#pragma unroll
      for (int i = 0; i < 4; ++i) {
        const int nl = cb * 64 + nq * 4 + i;
        const int key = ((nl >> 2) + 2 * (nl & 3)) & 7;
        uint32_t d0 = cvtpk_bf16(br[g][0][i], br[g][1][i]);
        uint32_t d1 = cvtpk_bf16(br[g][2][i], br[g][3][i]);
        *(uint2*)(Bsb + nl * 64 + (wave ^ key) * 8 + kq) = make_uint2(d0, d1);
      }
    }
  };

  fx4 acc[FM][FN];
#pragma unroll
  for (int a = 0; a < FM; ++a)
#pragma unroll
    for (int b = 0; b < FN; ++b) acc[a][b] = (fx4){0.f, 0.f, 0.f, 0.f};

  auto COMPUTE = [&](const unsigned short* Asb, const unsigned short* Bsb) {
#pragma unroll
    for (int kk = 0; kk < 2; ++kk) {
      bfx8 af[FM], bf[FN];
#pragma unroll
      for (int fm = 0; fm < FM; ++fm) {
        int r = wm * 128 + fm * 16 + (lane & 15);
        int c = (kk * 4 + (lane >> 4)) ^ (r & 7);
        af[fm] = *(const bfx8*)(Asb + r * 64 + c * 8);
      }
#pragma unroll
      for (int fn = 0; fn < FN; ++fn) {
        int nn = wn * (BN / 4) + fn * 16 + (lane & 15);
        int key = ((nn >> 2) + 2 * (nn & 3)) & 7;
        int c = (kk * 4 + (lane >> 4)) ^ key;
        bf[fn] = *(const bfx8*)(Bsb + nn * 64 + c * 8);
      }
#pragma unroll
      for (int fm = 0; fm < FM; ++fm)
#pragma unroll
        for (int fn = 0; fn < FN; ++fn)
          acc[fm][fn] = __builtin_amdgcn_mfma_f32_16x16x32_bf16(
              af[fm], bf[fn], acc[fm][fn], 0, 0, 0);
    }
  };

  // ---- prologue: tile 0 into buf 0 ----
  A_STAGE(0, As[0]);
  B_LOAD(0);
  B_STORE(Bs[0]);
  __syncthreads();

  // ---- main loop: 2-phase double-buffered ----
  for (int t = 0; t < NT; ++t) {
    const int c = t & 1;
    if (t + 1 < NT) {
      A_STAGE((t + 1) * BK, As[c ^ 1]);   // DMA, covered by COMPUTE below
      B_LOAD((t + 1) * BK);               // reg loads, covered by COMPUTE
    }
    COMPUTE(As[c], Bs[c]);                // ~64 MFMA/wave
    if (t + 1 < NT) B_STORE(Bs[c ^ 1]);   // cvt+ds_write after compute
    __syncthreads();
  }

  // ---- epilogue ----
  const int colbase = n0 + wn * (BN / 4);
  if (FIRST) {
#pragma unroll
    for (int fn = 0; fn < FN; ++fn) {
      int colg = colbase + fn * 16 + (lane & 15);
      float bv = Bias[(size_t)e * N_ + colg];
#pragma unroll
      for (int fm = 0; fm < FM; ++fm) {
        int rg = rowbase + wm * 128 + fm * 16 + ((lane >> 4) << 2);
#pragma unroll
        for (int j = 0; j < 4; ++j) {
          float v = fmaxf(acc[fm][fn][j] + bv, 0.f);
          Hout[(size_t)(rg + j) * N_ + colg] = f2bf(v);
        }
      }
    }
  } else {
#pragma unroll
    for (int fm = 0; fm < FM; ++fm) {
      int rg = rowbase + wm * 128 + fm * 16 + ((lane >> 4) << 2);
#pragma unroll
      for (int j = 0; j < 4; ++j) {
        int tok = perm_out[rg + j];
        if (tok < 0) continue;
        float pm = pmax[tok];
#pragma unroll
        for (int fn = 0; fn < FN; ++fn) {
          int colg = colbase + fn * 16 + (lane & 15);
          float v = acc[fm][fn][j];
          if (kz == 0) v += Bias[(size_t)e * N_ + colg];
          atomicAdd(&Out[(size_t)tok * N_ + colg], v * pm);
        }
      }
    }
  }
}

extern "C" void kernel_launch(void* const* d_in, const int* in_sizes, int n_in,
                              void* d_out, int out_size, void* d_ws, size_t ws_size,
                              hipStream_t stream) {
  const float* x  = (const float*)d_in[0];
  const float* sw = (const float*)d_in[1];
  const float* sb = (const float*)d_in[2];
  const float* w1 = (const float*)d_in[3];
  const float* b1 = (const float*)d_in[4];
  const float* w2 = (const float*)d_in[5];
  const float* b2 = (const float*)d_in[6];
  float* out = (float*)d_out;

  char* ws = (char*)d_ws;
  int*   off      = (int*)(ws + 0);          // 9 ints
  int*   routes   = (int*)(ws + 1024);       // 2048 ints
  int*   perm_out = (int*)(ws + 16384);      // RPMAX ints (pads -1)
  int*   perm_src = (int*)(ws + 32768);      // RPMAX ints (pads 0)
  float* probs    = (float*)(ws + 65536);    // 2048x8 fp32
  unsigned short* xbf = (unsigned short*)(ws + (1u << 20));   // 4 MB
  unsigned short* H   = (unsigned short*)(ws + (8u << 20));   // RPMAX x 4096 bf16 = 32 MB

  // d_out layout: final(2097152) | counts(8) | psums(8) | 0(1) | pmax(2048)
  float* out_final  = out;
  float* out_counts = out + 2097152;
  float* out_psums  = out + 2097160;
  float* out_zero   = out + 2097168;
  float* out_pmax   = out + 2097169;

  // split-K GEMM2 accumulates atomically into out_final -> zero it (custom kernel)
  zero_kernel<<<2048, 256, 0, stream>>>((float4*)out_final);

  router_kernel<<<T_TOK / 4, 256, 0, stream>>>(x, sw, sb, out_pmax, routes, probs, xbf);
  plan_kernel<<<1, 256, 0, stream>>>(routes, probs, off, perm_out, perm_src,
                                     out_counts, out_psums, out_zero);

  // GEMM1: gather(xbf)[RP,1024] x W1 -> H (relu, bf16). 256x256 tile,
  // grid 16x16=256 blocks (exact chip fill), n-chunked XCD swizzle.
  gemm256<256, D_DIM, F_DIM, 1, true>
      <<<dim3(F_DIM / 256, RPMAX / 256, 1), 512, 0, stream>>>(
          xbf, w1, b1, off, perm_src, perm_out, nullptr, H, nullptr);
  // GEMM2: H[RP,4096] x W2 -> out (bias, *pmax, scatter, atomic split-K=2).
  // 256x128 tile, grid 8x16x2=256 blocks, n-chunked.
  gemm256<128, F_DIM, D_DIM, 2, false>
      <<<dim3(D_DIM / 128, RPMAX / 256, 2), 512, 0, stream>>>(
          H, w2, b2, off, perm_src, perm_out, out_pmax, nullptr, out_final);
}